// Round 1
// baseline (2740.050 us; speedup 1.0000x reference)
//
#include <hip/hip_runtime.h>

#define DD 96
#define HH 4
#define HD 384
#define NEG_SLOPE 0.2f

// ---------------- GEMM: h = x @ W   (x:[N,96], W:[96,384], h:[N,384]) ----------------
// block = 128 threads, 8 nodes per block. Each thread computes 3 output cols per node.
__global__ void gemm_h_kernel(const float* __restrict__ x, const float* __restrict__ W,
                              float* __restrict__ h) {
    __shared__ float xs[8 * DD];
    const int t = threadIdx.x;           // 0..127
    const int n0 = blockIdx.x * 8;
    for (int idx = t; idx < 8 * DD; idx += 128) xs[idx] = x[(size_t)n0 * DD + idx];
    __syncthreads();

    float acc[8][3];
#pragma unroll
    for (int nn = 0; nn < 8; nn++)
#pragma unroll
        for (int j = 0; j < 3; j++) acc[nn][j] = 0.f;

    for (int k = 0; k < DD; k++) {
        const float w0 = W[k * HD + t];
        const float w1 = W[k * HD + t + 128];
        const float w2 = W[k * HD + t + 256];
#pragma unroll
        for (int nn = 0; nn < 8; nn++) {
            const float xv = xs[nn * DD + k];
            acc[nn][0] = fmaf(xv, w0, acc[nn][0]);
            acc[nn][1] = fmaf(xv, w1, acc[nn][1]);
            acc[nn][2] = fmaf(xv, w2, acc[nn][2]);
        }
    }
#pragma unroll
    for (int nn = 0; nn < 8; nn++) {
        float* hr = h + (size_t)(n0 + nn) * HD;
        hr[t]       = acc[nn][0];
        hr[t + 128] = acc[nn][1];
        hr[t + 256] = acc[nn][2];
    }
}

// ---------------- per-(node,head) attention logit halves ----------------
__global__ void alpha_kernel(const float* __restrict__ h,
                             const float* __restrict__ aw_src,
                             const float* __restrict__ aw_dst,
                             float* __restrict__ asrc, float* __restrict__ adst, int NH) {
    const int i = blockIdx.x * blockDim.x + threadIdx.x;
    if (i >= NH) return;
    const int n = i >> 2, head = i & 3;
    const float* hr = h + (size_t)n * HD + head * DD;
    const float* aw = aw_src + head * DD;
    const float* bw = aw_dst + head * DD;
    float s = 0.f, d2 = 0.f;
#pragma unroll 4
    for (int k = 0; k < DD; k++) {
        const float v = hr[k];
        s  = fmaf(v, aw[k], s);
        d2 = fmaf(v, bw[k], d2);
    }
    asrc[i] = s;
    adst[i] = d2;
}

// ---------------- pass 1: softmax denominators (no max-shift; exp args bounded) ------
__global__ void denom_kernel(const int* __restrict__ ei,
                             const float* __restrict__ asrc, const float* __restrict__ adst,
                             float* __restrict__ denom, int E, int Etot) {
    int i = blockIdx.x * blockDim.x + threadIdx.x;
    const int stride = gridDim.x * blockDim.x;
    for (; i < Etot; i += stride) {
        int src, dst;
        if (i < E) { src = ei[i]; dst = ei[E + i]; } else { src = dst = i - E; }
#pragma unroll
        for (int hh = 0; hh < HH; hh++) {
            float e = asrc[src * HH + hh] + adst[dst * HH + hh];
            e = e > 0.f ? e : NEG_SLOPE * e;
            unsafeAtomicAdd(&denom[dst * HH + hh], __expf(e));
        }
    }
}

// ---------------- pass 2: aggregate messages, one wave per edge ----------------
__global__ void agg_kernel(const int* __restrict__ ei, const float* __restrict__ h,
                           const float* __restrict__ asrc, const float* __restrict__ adst,
                           const float* __restrict__ denom, float* __restrict__ out,
                           int E, int Etot) {
    const int lane = threadIdx.x & 63;
    int wid = (blockIdx.x * blockDim.x + threadIdx.x) >> 6;
    const int nw = (gridDim.x * blockDim.x) >> 6;
    for (int e = wid; e < Etot; e += nw) {
        int src, dst;
        if (e < E) { src = ei[e]; dst = ei[E + e]; } else { src = dst = e - E; }
        float c[HH];
#pragma unroll
        for (int hh = 0; hh < HH; hh++) {
            float ev = asrc[src * HH + hh] + adst[dst * HH + hh];
            ev = ev > 0.f ? ev : NEG_SLOPE * ev;
            c[hh] = __expf(ev) / (denom[dst * HH + hh] + 1e-16f);
        }
        const float* hs = h + (size_t)src * HD;
        float* od = out + (size_t)dst * HD;
#pragma unroll
        for (int j = 0; j < 6; j++) {
            const int idx = lane + j * 64;
            const int hh = idx / DD;
            const float cf = hh == 0 ? c[0] : (hh == 1 ? c[1] : (hh == 2 ? c[2] : c[3]));
            unsafeAtomicAdd(&od[idx], hs[idx] * cf);
        }
    }
}

// ---------------- head mean + bias, BN partial sums ----------------
// gridDim.x*blockDim.x must be a multiple of 96 so each thread owns a fixed feature d.
__global__ void mean_bn_kernel(const float* __restrict__ out, const float* __restrict__ bias,
                               float* __restrict__ y, float* __restrict__ bnsum,
                               float* __restrict__ bnsq, int N) {
    const int gtid = blockIdx.x * blockDim.x + threadIdx.x;
    const int G = gridDim.x * blockDim.x;
    const int d = gtid % DD;
    const float b = bias[d];
    float s = 0.f, s2 = 0.f;
    for (int i = gtid; i < N * DD; i += G) {
        const int n = i / DD;
        const float* o = out + (size_t)n * HD + d;
        const float v = 0.25f * (o[0] + o[DD] + o[2 * DD] + o[3 * DD]) + b;
        y[i] = v;
        s += v;
        s2 = fmaf(v, v, s2);
    }
    unsafeAtomicAdd(&bnsum[d], s);
    unsafeAtomicAdd(&bnsq[d], s2);
}

// ---------------- BN apply + ReLU + residual ----------------
__global__ void bn_apply_kernel(const float* __restrict__ y,
                                const float* __restrict__ bnsum, const float* __restrict__ bnsq,
                                const float* __restrict__ gamma, const float* __restrict__ beta,
                                const float* __restrict__ xin, float* __restrict__ xout, int N) {
    int i = blockIdx.x * blockDim.x + threadIdx.x;
    const int stride = gridDim.x * blockDim.x;
    const float invN = 1.f / (float)N;
    for (; i < N * DD; i += stride) {
        const int d = i % DD;
        const float mu = bnsum[d] * invN;
        const float var = bnsq[d] * invN - mu * mu;
        const float rstd = rsqrtf(var + 1e-5f);
        float v = (y[i] - mu) * rstd * gamma[d] + beta[d];
        v = v > 0.f ? v : 0.f;
        xout[i] = v + xin[i];
    }
}

extern "C" void kernel_launch(void* const* d_in, const int* in_sizes, int n_in,
                              void* d_out, int out_size, void* d_ws, size_t ws_size,
                              hipStream_t stream) {
    const float* x        = (const float*)d_in[0];
    const int*   ei       = (const int*)d_in[1];
    const float* W        = (const float*)d_in[2];
    const float* att_src  = (const float*)d_in[3];
    const float* att_dst  = (const float*)d_in[4];
    const float* bias     = (const float*)d_in[5];
    const float* gamma    = (const float*)d_in[6];
    const float* beta     = (const float*)d_in[7];
    float* out_final = (float*)d_out;

    const int N = in_sizes[0] / DD;     // 50000
    const int E = in_sizes[1] / 2;      // 800000
    const int Etot = E + N;

    char* ws = (char*)d_ws;
    size_t off = 0;
    auto alloc = [&](size_t bytes) -> void* {
        void* p = ws + off;
        off += (bytes + 255) & ~(size_t)255;
        return p;
    };
    float* h      = (float*)alloc((size_t)N * HD * 4);
    float* outacc = (float*)alloc((size_t)N * HD * 4);
    float* asrc   = (float*)alloc((size_t)N * HH * 4);
    float* adst   = (float*)alloc((size_t)N * HH * 4);
    float* denom  = (float*)alloc((size_t)N * HH * 4);
    float* bnsum  = (float*)alloc(2 * DD * 4);      // bnsum[96] then bnsq[96]
    float* xbuf   = (float*)alloc((size_t)N * DD * 4);
    float* bnsq   = bnsum + DD;

    for (int l = 0; l < 2; l++) {
        const float* xin = (l == 0) ? x : xbuf;
        float* xout = (l == 1) ? out_final : xbuf;

        hipMemsetAsync(denom, 0, (size_t)N * HH * 4, stream);
        hipMemsetAsync(outacc, 0, (size_t)N * HD * 4, stream);
        hipMemsetAsync(bnsum, 0, 2 * DD * 4, stream);

        gemm_h_kernel<<<N / 8, 128, 0, stream>>>(xin, W + (size_t)l * DD * HD, h);
        alpha_kernel<<<(N * HH + 255) / 256, 256, 0, stream>>>(
            h, att_src + l * HD, att_dst + l * HD, asrc, adst, N * HH);
        denom_kernel<<<4096, 256, 0, stream>>>(ei, asrc, adst, denom, E, Etot);
        agg_kernel<<<(Etot + 3) / 4, 256, 0, stream>>>(ei, h, asrc, adst, denom, outacc, E, Etot);
        // y reuses the h buffer (h is dead after agg_kernel)
        mean_bn_kernel<<<512, 384, 0, stream>>>(outacc, bias + l * DD, h, bnsum, bnsq, N);
        bn_apply_kernel<<<2048, 256, 0, stream>>>(h, bnsum, bnsq, gamma + l * DD,
                                                  beta + l * DD, xin, xout, N);
    }
}

// Round 2
// 856.641 us; speedup vs baseline: 3.1986x; 3.1986x over previous
//
#include <hip/hip_runtime.h>

#define DD 96
#define HH 4
#define HD 384
#define NEG_SLOPE 0.2f

// ---------------- GEMM: h = x @ W   (x:[N,96], W:[96,384], h:[N,384]) ----------------
__global__ void gemm_h_kernel(const float* __restrict__ x, const float* __restrict__ W,
                              float* __restrict__ h) {
    __shared__ float xs[8 * DD];
    const int t = threadIdx.x;           // 0..127
    const int n0 = blockIdx.x * 8;
    for (int idx = t; idx < 8 * DD; idx += 128) xs[idx] = x[(size_t)n0 * DD + idx];
    __syncthreads();

    float acc[8][3];
#pragma unroll
    for (int nn = 0; nn < 8; nn++)
#pragma unroll
        for (int j = 0; j < 3; j++) acc[nn][j] = 0.f;

    for (int k = 0; k < DD; k++) {
        const float w0 = W[k * HD + t];
        const float w1 = W[k * HD + t + 128];
        const float w2 = W[k * HD + t + 256];
#pragma unroll
        for (int nn = 0; nn < 8; nn++) {
            const float xv = xs[nn * DD + k];
            acc[nn][0] = fmaf(xv, w0, acc[nn][0]);
            acc[nn][1] = fmaf(xv, w1, acc[nn][1]);
            acc[nn][2] = fmaf(xv, w2, acc[nn][2]);
        }
    }
#pragma unroll
    for (int nn = 0; nn < 8; nn++) {
        float* hr = h + (size_t)(n0 + nn) * HD;
        hr[t]       = acc[nn][0];
        hr[t + 128] = acc[nn][1];
        hr[t + 256] = acc[nn][2];
    }
}

// ---------------- per-(node,head) attention logit halves ----------------
__global__ void alpha_kernel(const float* __restrict__ h,
                             const float* __restrict__ aw_src,
                             const float* __restrict__ aw_dst,
                             float* __restrict__ asrc, float* __restrict__ adst, int NH) {
    const int i = blockIdx.x * blockDim.x + threadIdx.x;
    if (i >= NH) return;
    const int n = i >> 2, head = i & 3;
    const float* hr = h + (size_t)n * HD + head * DD;
    const float* aw = aw_src + head * DD;
    const float* bw = aw_dst + head * DD;
    float s = 0.f, d2 = 0.f;
#pragma unroll 4
    for (int k = 0; k < DD; k++) {
        const float v = hr[k];
        s  = fmaf(v, aw[k], s);
        d2 = fmaf(v, bw[k], d2);
    }
    asrc[i] = s;
    adst[i] = d2;
}

// ---------------- CSR build: degree count, scan, scatter ----------------
__global__ void deg_init_kernel(int* __restrict__ deg, int N) {
    int i = blockIdx.x * blockDim.x + threadIdx.x;
    if (i < N) deg[i] = 1;   // self-loop
}

__global__ void count_kernel(const int* __restrict__ ei, int* __restrict__ deg, int E) {
    int i = blockIdx.x * blockDim.x + threadIdx.x;
    const int stride = gridDim.x * blockDim.x;
    for (; i < E; i += stride) atomicAdd(&deg[ei[E + i]], 1);
}

// single-block exclusive scan over deg[N] -> rowptr[N+1]
__global__ void scan_kernel(const int* __restrict__ deg, int* __restrict__ rowptr, int N) {
    __shared__ int lsum[1024];
    const int t = threadIdx.x;
    const int per = (N + 1023) / 1024;
    const int start = t * per;
    const int end = min(start + per, N);
    int s = 0;
    for (int i = start; i < end; i++) s += deg[i];
    lsum[t] = s;
    __syncthreads();
    for (int off = 1; off < 1024; off <<= 1) {
        int u = (t >= off) ? lsum[t - off] : 0;
        __syncthreads();
        lsum[t] += u;
        __syncthreads();
    }
    int run = lsum[t] - s;   // exclusive prefix for this thread's chunk
    for (int i = start; i < end; i++) { rowptr[i] = run; run += deg[i]; }
    if (t == 1023) rowptr[N] = lsum[1023];
}

__global__ void scatter_kernel(const int* __restrict__ ei, int* __restrict__ cursor,
                               int* __restrict__ col, int E, int Etot) {
    int i = blockIdx.x * blockDim.x + threadIdx.x;
    const int stride = gridDim.x * blockDim.x;
    for (; i < Etot; i += stride) {
        int src, dst;
        if (i < E) { src = ei[i]; dst = ei[E + i]; } else { src = dst = i - E; }
        const int pos = atomicAdd(&cursor[dst], 1);
        col[pos] = src;
    }
}

// ---------------- fused aggregate: softmax + weighted sum + head-mean + bias --------
// one wave per destination node; 6 f32 accumulators/lane cover the 384-wide row.
__global__ void agg_csr_kernel(const int* __restrict__ rowptr, const int* __restrict__ col,
                               const float* __restrict__ h, const float* __restrict__ asrc,
                               const float* __restrict__ adst, const float* __restrict__ bias,
                               float* __restrict__ y, int N) {
    const int lane = threadIdx.x & 63;
    const bool hi32 = lane >= 32;
    const int w0id = (blockIdx.x * blockDim.x + threadIdx.x) >> 6;
    const int nw = (gridDim.x * blockDim.x) >> 6;
    for (int n = w0id; n < N; n += nw) {
        const int beg = rowptr[n], endp = rowptr[n + 1];
        const float4 adv = *(const float4*)(adst + (size_t)n * 4);
        float acc0 = 0.f, acc1 = 0.f, acc2 = 0.f, acc3 = 0.f, acc4 = 0.f, acc5 = 0.f;
        float den0 = 0.f, den1 = 0.f, den2 = 0.f, den3 = 0.f;
        for (int e = beg; e < endp; e++) {
            const int src = col[e];
            const float4 av = *(const float4*)(asrc + (size_t)src * 4);
            float e0 = av.x + adv.x, e1 = av.y + adv.y, e2 = av.z + adv.z, e3 = av.w + adv.w;
            e0 = e0 > 0.f ? e0 : NEG_SLOPE * e0;
            e1 = e1 > 0.f ? e1 : NEG_SLOPE * e1;
            e2 = e2 > 0.f ? e2 : NEG_SLOPE * e2;
            e3 = e3 > 0.f ? e3 : NEG_SLOPE * e3;
            const float w0 = __expf(e0), w1 = __expf(e1), w2 = __expf(e2), w3 = __expf(e3);
            den0 += w0; den1 += w1; den2 += w2; den3 += w3;
            const float cf1 = hi32 ? w1 : w0;   // j=1 spans head0|head1 at lane 32
            const float cf4 = hi32 ? w3 : w2;   // j=4 spans head2|head3 at lane 32
            const float* hs = h + (size_t)src * HD + lane;
            acc0 = fmaf(hs[0],   w0,  acc0);
            acc1 = fmaf(hs[64],  cf1, acc1);
            acc2 = fmaf(hs[128], w1,  acc2);
            acc3 = fmaf(hs[192], w2,  acc3);
            acc4 = fmaf(hs[256], cf4, acc4);
            acc5 = fmaf(hs[320], w3,  acc5);
        }
        const float r0 = 1.f / (den0 + 1e-16f);
        const float r1 = 1.f / (den1 + 1e-16f);
        const float r2 = 1.f / (den2 + 1e-16f);
        const float r3 = 1.f / (den3 + 1e-16f);
        const float rc1 = hi32 ? r1 : r0;
        const float rc4 = hi32 ? r3 : r2;
        // head-mean via lane^32 pairing:
        // A_l = out[l] + out[l+192]; B_l = out[l+64..]+out[l+256..]; C_l = out[l+128..]+out[l+320..]
        const float A = acc0 * r0  + acc3 * r2;
        const float B = acc1 * rc1 + acc4 * rc4;
        const float C = acc2 * r1  + acc5 * r3;
        const float shB = __shfl_xor(B, 32);
        const float shC = __shfl_xor(C, 32);
        float* yr = y + (size_t)n * DD;
        yr[lane] = 0.25f * (A + (hi32 ? shC : shB)) + bias[lane];
        if (!hi32) yr[64 + lane] = 0.25f * (B + shC) + bias[64 + lane];
    }
}

// ---------------- BN batch statistics over y [N,96] ----------------
__global__ void bnstats_kernel(const float* __restrict__ y, float* __restrict__ bnsum,
                               float* __restrict__ bnsq, int total) {
    const int gtid = blockIdx.x * blockDim.x + threadIdx.x;
    const int G = gridDim.x * blockDim.x;      // multiple of 96
    const int d = gtid % DD;
    float s = 0.f, s2 = 0.f;
    for (int i = gtid; i < total; i += G) {
        const float v = y[i];
        s += v;
        s2 = fmaf(v, v, s2);
    }
    unsafeAtomicAdd(&bnsum[d], s);
    unsafeAtomicAdd(&bnsq[d], s2);
}

// ---------------- BN apply + ReLU + residual ----------------
__global__ void bn_apply_kernel(const float* __restrict__ y,
                                const float* __restrict__ bnsum, const float* __restrict__ bnsq,
                                const float* __restrict__ gamma, const float* __restrict__ beta,
                                const float* __restrict__ xin, float* __restrict__ xout, int N) {
    int i = blockIdx.x * blockDim.x + threadIdx.x;
    const int stride = gridDim.x * blockDim.x;
    const float invN = 1.f / (float)N;
    for (; i < N * DD; i += stride) {
        const int d = i % DD;
        const float mu = bnsum[d] * invN;
        const float var = bnsq[d] * invN - mu * mu;
        const float rstd = rsqrtf(var + 1e-5f);
        float v = (y[i] - mu) * rstd * gamma[d] + beta[d];
        v = v > 0.f ? v : 0.f;
        xout[i] = v + xin[i];
    }
}

extern "C" void kernel_launch(void* const* d_in, const int* in_sizes, int n_in,
                              void* d_out, int out_size, void* d_ws, size_t ws_size,
                              hipStream_t stream) {
    const float* x        = (const float*)d_in[0];
    const int*   ei       = (const int*)d_in[1];
    const float* W        = (const float*)d_in[2];
    const float* att_src  = (const float*)d_in[3];
    const float* att_dst  = (const float*)d_in[4];
    const float* bias     = (const float*)d_in[5];
    const float* gamma    = (const float*)d_in[6];
    const float* beta     = (const float*)d_in[7];
    float* out_final = (float*)d_out;

    const int N = in_sizes[0] / DD;     // 50000
    const int E = in_sizes[1] / 2;      // 800000
    const int Etot = E + N;

    char* ws = (char*)d_ws;
    size_t off = 0;
    auto alloc = [&](size_t bytes) -> void* {
        void* p = ws + off;
        off += (bytes + 255) & ~(size_t)255;
        return p;
    };
    float* h      = (float*)alloc((size_t)N * HD * 4);
    float* asrc   = (float*)alloc((size_t)N * HH * 4);
    float* adst   = (float*)alloc((size_t)N * HH * 4);
    float* y      = (float*)alloc((size_t)N * DD * 4);
    float* xbuf   = (float*)alloc((size_t)N * DD * 4);
    float* bnsum  = (float*)alloc(2 * DD * 4);
    int*   deg    = (int*)alloc((size_t)N * 4);
    int*   rowptr = (int*)alloc((size_t)(N + 1) * 4);
    int*   cursor = (int*)alloc((size_t)N * 4);
    int*   colidx = (int*)alloc((size_t)Etot * 4);
    float* bnsq   = bnsum + DD;

    // ---- CSR by destination (once per call; edge structure is layer-invariant) ----
    deg_init_kernel<<<(N + 255) / 256, 256, 0, stream>>>(deg, N);
    count_kernel<<<1024, 256, 0, stream>>>(ei, deg, E);
    scan_kernel<<<1, 1024, 0, stream>>>(deg, rowptr, N);
    hipMemcpyAsync(cursor, rowptr, (size_t)N * 4, hipMemcpyDeviceToDevice, stream);
    scatter_kernel<<<1024, 256, 0, stream>>>(ei, cursor, colidx, E, Etot);

    for (int l = 0; l < 2; l++) {
        const float* xin = (l == 0) ? x : xbuf;
        float* xout = (l == 1) ? out_final : xbuf;

        hipMemsetAsync(bnsum, 0, 2 * DD * 4, stream);

        gemm_h_kernel<<<N / 8, 128, 0, stream>>>(xin, W + (size_t)l * DD * HD, h);
        alpha_kernel<<<(N * HH + 255) / 256, 256, 0, stream>>>(
            h, att_src + (size_t)l * HD, att_dst + (size_t)l * HD, asrc, adst, N * HH);
        agg_csr_kernel<<<(N * 64 + 255) / 256, 256, 0, stream>>>(
            rowptr, colidx, h, asrc, adst, bias + (size_t)l * DD, y, N);
        bnstats_kernel<<<256, 384, 0, stream>>>(y, bnsum, bnsq, N * DD);
        bn_apply_kernel<<<2048, 256, 0, stream>>>(y, bnsum, bnsq, gamma + (size_t)l * DD,
                                                  beta + (size_t)l * DD, xin, xout, N);
    }
}

// Round 3
// 691.503 us; speedup vs baseline: 3.9625x; 1.2388x over previous
//
#include <hip/hip_runtime.h>

#define DD 96
#define HH 4
#define HD 384
#define NEG_SLOPE 0.2f

typedef unsigned int uint;
typedef unsigned short ushort;

__device__ inline ushort f2bf(float f) {           // round-to-nearest-even bf16
    uint u = __float_as_uint(f);
    u += 0x7fffu + ((u >> 16) & 1u);
    return (ushort)(u >> 16);
}
__device__ inline float bf2f(ushort s) { return __uint_as_float(((uint)s) << 16); }

// ---------------- GEMM: h = x @ W -> bf16   (x:[N,96] f32, W:[96,384] f32) ----------
// 128 threads, 16 nodes/block; thread t computes cols t, t+128, t+256.
__global__ void gemm_h_kernel(const float* __restrict__ x, const float* __restrict__ W,
                              ushort* __restrict__ h) {
    __shared__ float xs[16 * DD];
    const int t = threadIdx.x;           // 0..127
    const int n0 = blockIdx.x * 16;
    const float4* xv4 = (const float4*)(x + (size_t)n0 * DD);
#pragma unroll
    for (int j = 0; j < 3; j++) ((float4*)xs)[t + j * 128] = xv4[t + j * 128];
    __syncthreads();

    float acc[16][3];
#pragma unroll
    for (int nn = 0; nn < 16; nn++)
#pragma unroll
        for (int j = 0; j < 3; j++) acc[nn][j] = 0.f;

    for (int k = 0; k < DD; k++) {
        const float w0 = W[k * HD + t];
        const float w1 = W[k * HD + t + 128];
        const float w2 = W[k * HD + t + 256];
#pragma unroll
        for (int nn = 0; nn < 16; nn++) {
            const float xv = xs[nn * DD + k];
            acc[nn][0] = fmaf(xv, w0, acc[nn][0]);
            acc[nn][1] = fmaf(xv, w1, acc[nn][1]);
            acc[nn][2] = fmaf(xv, w2, acc[nn][2]);
        }
    }
#pragma unroll
    for (int nn = 0; nn < 16; nn++) {
        ushort* hr = h + (size_t)(n0 + nn) * HD;
        hr[t]       = f2bf(acc[nn][0]);
        hr[t + 128] = f2bf(acc[nn][1]);
        hr[t + 256] = f2bf(acc[nn][2]);
    }
}

// ---------------- per-(node,head) attention logit halves ----------------
__global__ void alpha_kernel(const ushort* __restrict__ h,
                             const float* __restrict__ aw_src,
                             const float* __restrict__ aw_dst,
                             float* __restrict__ asrc, float* __restrict__ adst, int NH) {
    const int i = blockIdx.x * blockDim.x + threadIdx.x;
    if (i >= NH) return;
    const int n = i >> 2, head = i & 3;
    const uint4* hp = (const uint4*)(h + (size_t)n * HD + head * DD);
    const float* aw = aw_src + head * DD;
    const float* bw = aw_dst + head * DD;
    float s = 0.f, d2 = 0.f;
#pragma unroll
    for (int v = 0; v < 12; v++) {
        const uint4 q = hp[v];
        const float* a8 = aw + v * 8;
        const float* b8 = bw + v * 8;
        const uint us[4] = {q.x, q.y, q.z, q.w};
#pragma unroll
        for (int p = 0; p < 4; p++) {
            const float f0 = __uint_as_float(us[p] << 16);
            const float f1 = __uint_as_float(us[p] & 0xffff0000u);
            s  = fmaf(f0, a8[2 * p], s);      d2 = fmaf(f0, b8[2 * p], d2);
            s  = fmaf(f1, a8[2 * p + 1], s);  d2 = fmaf(f1, b8[2 * p + 1], d2);
        }
    }
    asrc[i] = s;
    adst[i] = d2;
}

// ---------------- CSR build: degree count, scan, scatter ----------------
__global__ void deg_init_kernel(int* __restrict__ deg, int N) {
    int i = blockIdx.x * blockDim.x + threadIdx.x;
    if (i < N) deg[i] = 1;   // self-loop
}

__global__ void count_kernel(const int* __restrict__ ei, int* __restrict__ deg, int E) {
    int i = blockIdx.x * blockDim.x + threadIdx.x;
    const int stride = gridDim.x * blockDim.x;
    for (; i < E; i += stride) atomicAdd(&deg[ei[E + i]], 1);
}

__global__ void scan_kernel(const int* __restrict__ deg, int* __restrict__ rowptr, int N) {
    __shared__ int lsum[1024];
    const int t = threadIdx.x;
    const int per = (N + 1023) / 1024;
    const int start = t * per;
    const int end = min(start + per, N);
    int s = 0;
    for (int i = start; i < end; i++) s += deg[i];
    lsum[t] = s;
    __syncthreads();
    for (int off = 1; off < 1024; off <<= 1) {
        int u = (t >= off) ? lsum[t - off] : 0;
        __syncthreads();
        lsum[t] += u;
        __syncthreads();
    }
    int run = lsum[t] - s;
    for (int i = start; i < end; i++) { rowptr[i] = run; run += deg[i]; }
    if (t == 1023) rowptr[N] = lsum[1023];
}

__global__ void scatter_kernel(const int* __restrict__ ei, int* __restrict__ cursor,
                               int* __restrict__ col, int E, int Etot) {
    int i = blockIdx.x * blockDim.x + threadIdx.x;
    const int stride = gridDim.x * blockDim.x;
    for (; i < Etot; i += stride) {
        int src, dst;
        if (i < E) { src = ei[i]; dst = ei[E + i]; } else { src = dst = i - E; }
        const int pos = atomicAdd(&cursor[dst], 1);
        col[pos] = src;
    }
}

// ---------------- fused aggregate: softmax + weighted sum + head-mean + bias --------
__global__ void agg_csr_kernel(const int* __restrict__ rowptr, const int* __restrict__ col,
                               const ushort* __restrict__ h, const float* __restrict__ asrc,
                               const float* __restrict__ adst, const float* __restrict__ bias,
                               float* __restrict__ y, int N) {
    const int lane = threadIdx.x & 63;
    const bool hi32 = lane >= 32;
    const int w0id = (blockIdx.x * blockDim.x + threadIdx.x) >> 6;
    const int nw = (gridDim.x * blockDim.x) >> 6;
    for (int n = w0id; n < N; n += nw) {
        const int beg = rowptr[n], endp = rowptr[n + 1];
        const float4 adv = *(const float4*)(adst + (size_t)n * 4);
        float acc0 = 0.f, acc1 = 0.f, acc2 = 0.f, acc3 = 0.f, acc4 = 0.f, acc5 = 0.f;
        float den0 = 0.f, den1 = 0.f, den2 = 0.f, den3 = 0.f;
        for (int e = beg; e < endp; e++) {
            const int src = col[e];
            const float4 av = *(const float4*)(asrc + (size_t)src * 4);
            float e0 = av.x + adv.x, e1 = av.y + adv.y, e2 = av.z + adv.z, e3 = av.w + adv.w;
            e0 = e0 > 0.f ? e0 : NEG_SLOPE * e0;
            e1 = e1 > 0.f ? e1 : NEG_SLOPE * e1;
            e2 = e2 > 0.f ? e2 : NEG_SLOPE * e2;
            e3 = e3 > 0.f ? e3 : NEG_SLOPE * e3;
            const float w0 = __expf(e0), w1 = __expf(e1), w2 = __expf(e2), w3 = __expf(e3);
            den0 += w0; den1 += w1; den2 += w2; den3 += w3;
            const float cf1 = hi32 ? w1 : w0;   // j=1 spans head0|head1 at lane 32
            const float cf4 = hi32 ? w3 : w2;   // j=4 spans head2|head3 at lane 32
            const ushort* hs = h + (size_t)src * HD + lane;
            acc0 = fmaf(bf2f(hs[0]),   w0,  acc0);
            acc1 = fmaf(bf2f(hs[64]),  cf1, acc1);
            acc2 = fmaf(bf2f(hs[128]), w1,  acc2);
            acc3 = fmaf(bf2f(hs[192]), w2,  acc3);
            acc4 = fmaf(bf2f(hs[256]), cf4, acc4);
            acc5 = fmaf(bf2f(hs[320]), w3,  acc5);
        }
        const float r0 = 1.f / (den0 + 1e-16f);
        const float r1 = 1.f / (den1 + 1e-16f);
        const float r2 = 1.f / (den2 + 1e-16f);
        const float r3 = 1.f / (den3 + 1e-16f);
        const float rc1 = hi32 ? r1 : r0;
        const float rc4 = hi32 ? r3 : r2;
        const float A = acc0 * r0  + acc3 * r2;
        const float B = acc1 * rc1 + acc4 * rc4;
        const float C = acc2 * r1  + acc5 * r3;
        const float shB = __shfl_xor(B, 32);
        const float shC = __shfl_xor(C, 32);
        float* yr = y + (size_t)n * DD;
        yr[lane] = 0.25f * (A + (hi32 ? shC : shB)) + bias[lane];
        if (!hi32) yr[64 + lane] = 0.25f * (B + shC) + bias[64 + lane];
    }
}

// ---------------- BN batch statistics over y [N,96] ----------------
__global__ void bnstats_kernel(const float* __restrict__ y, float* __restrict__ bnsum,
                               float* __restrict__ bnsq, int total) {
    const int gtid = blockIdx.x * blockDim.x + threadIdx.x;
    const int G = gridDim.x * blockDim.x;      // multiple of 96
    const int d = gtid % DD;
    float s = 0.f, s2 = 0.f;
    for (int i = gtid; i < total; i += G) {
        const float v = y[i];
        s += v;
        s2 = fmaf(v, v, s2);
    }
    unsafeAtomicAdd(&bnsum[d], s);
    unsafeAtomicAdd(&bnsq[d], s2);
}

// ---------------- BN finalize: scale/shift per feature ----------------
__global__ void bnfin_kernel(const float* __restrict__ bnsum, const float* __restrict__ bnsq,
                             const float* __restrict__ gamma, const float* __restrict__ beta,
                             float* __restrict__ scsh, int N) {
    const int d = threadIdx.x;   // 96 threads
    const float invN = 1.f / (float)N;
    const float mu = bnsum[d] * invN;
    const float var = bnsq[d] * invN - mu * mu;
    const float sc = gamma[d] * rsqrtf(var + 1e-5f);
    scsh[d] = sc;
    scsh[d + DD] = beta[d] - mu * sc;
}

// ---------------- BN apply + ReLU + residual (float4) ----------------
__global__ void bn_apply_kernel(const float* __restrict__ y, const float* __restrict__ scsh,
                                const float* __restrict__ xin, float* __restrict__ xout,
                                int total4) {
    int i = blockIdx.x * blockDim.x + threadIdx.x;
    const int stride = gridDim.x * blockDim.x;
    for (; i < total4; i += stride) {
        const int d4 = (i % 24) * 4;
        const float4 v = ((const float4*)y)[i];
        const float4 xi = ((const float4*)xin)[i];
        float4 o;
        float a;
        a = fmaf(v.x, scsh[d4],     scsh[d4 + DD]);     o.x = (a > 0.f ? a : 0.f) + xi.x;
        a = fmaf(v.y, scsh[d4 + 1], scsh[d4 + 1 + DD]); o.y = (a > 0.f ? a : 0.f) + xi.y;
        a = fmaf(v.z, scsh[d4 + 2], scsh[d4 + 2 + DD]); o.z = (a > 0.f ? a : 0.f) + xi.z;
        a = fmaf(v.w, scsh[d4 + 3], scsh[d4 + 3 + DD]); o.w = (a > 0.f ? a : 0.f) + xi.w;
        ((float4*)xout)[i] = o;
    }
}

extern "C" void kernel_launch(void* const* d_in, const int* in_sizes, int n_in,
                              void* d_out, int out_size, void* d_ws, size_t ws_size,
                              hipStream_t stream) {
    const float* x        = (const float*)d_in[0];
    const int*   ei       = (const int*)d_in[1];
    const float* W        = (const float*)d_in[2];
    const float* att_src  = (const float*)d_in[3];
    const float* att_dst  = (const float*)d_in[4];
    const float* bias     = (const float*)d_in[5];
    const float* gamma    = (const float*)d_in[6];
    const float* beta     = (const float*)d_in[7];
    float* out_final = (float*)d_out;

    const int N = in_sizes[0] / DD;     // 50000
    const int E = in_sizes[1] / 2;      // 800000
    const int Etot = E + N;

    char* ws = (char*)d_ws;
    size_t off = 0;
    auto alloc = [&](size_t bytes) -> void* {
        void* p = ws + off;
        off += (bytes + 255) & ~(size_t)255;
        return p;
    };
    ushort* h     = (ushort*)alloc((size_t)N * HD * 2);
    float* asrc   = (float*)alloc((size_t)N * HH * 4);
    float* adst   = (float*)alloc((size_t)N * HH * 4);
    float* y      = (float*)alloc((size_t)N * DD * 4);
    float* xbuf   = (float*)alloc((size_t)N * DD * 4);
    float* bnsum  = (float*)alloc(2 * DD * 4);
    float* scsh   = (float*)alloc(2 * DD * 4);
    int*   deg    = (int*)alloc((size_t)N * 4);
    int*   rowptr = (int*)alloc((size_t)(N + 1) * 4);
    int*   cursor = (int*)alloc((size_t)N * 4);
    int*   colidx = (int*)alloc((size_t)Etot * 4);
    float* bnsq   = bnsum + DD;

    // ---- CSR by destination (edge structure is layer-invariant) ----
    deg_init_kernel<<<(N + 255) / 256, 256, 0, stream>>>(deg, N);
    count_kernel<<<1024, 256, 0, stream>>>(ei, deg, E);
    scan_kernel<<<1, 1024, 0, stream>>>(deg, rowptr, N);
    hipMemcpyAsync(cursor, rowptr, (size_t)N * 4, hipMemcpyDeviceToDevice, stream);
    scatter_kernel<<<1024, 256, 0, stream>>>(ei, cursor, colidx, E, Etot);

    for (int l = 0; l < 2; l++) {
        const float* xin = (l == 0) ? x : xbuf;
        float* xout = (l == 1) ? out_final : xbuf;

        hipMemsetAsync(bnsum, 0, 2 * DD * 4, stream);

        gemm_h_kernel<<<N / 16, 128, 0, stream>>>(xin, W + (size_t)l * DD * HD, h);
        alpha_kernel<<<(N * HH + 255) / 256, 256, 0, stream>>>(
            h, att_src + (size_t)l * HD, att_dst + (size_t)l * HD, asrc, adst, N * HH);
        agg_csr_kernel<<<(N * 64 + 255) / 256, 256, 0, stream>>>(
            rowptr, colidx, h, asrc, adst, bias + (size_t)l * DD, y, N);
        bnstats_kernel<<<256, 384, 0, stream>>>(y, bnsum, bnsq, N * DD);
        bnfin_kernel<<<1, DD, 0, stream>>>(bnsum, bnsq, gamma + (size_t)l * DD,
                                           beta + (size_t)l * DD, scsh, N);
        bn_apply_kernel<<<2048, 256, 0, stream>>>(y, scsh, xin, xout, N * DD / 4);
    }
}

// Round 4
// 569.076 us; speedup vs baseline: 4.8149x; 1.2151x over previous
//
#include <hip/hip_runtime.h>

#define DD 96
#define HH 4
#define HD 384
#define GN 32            // nodes per gemm block
#define NEG_SLOPE 0.2f
#define NB_STATS 128     // bnstats blocks

typedef unsigned int uint;
typedef unsigned short ushort;

__device__ inline uint pack2bf(float lo, float hi) {   // round-to-nearest-even both halves
    uint ulo = __float_as_uint(lo); ulo += 0x7fffu + ((ulo >> 16) & 1u);
    uint uhi = __float_as_uint(hi); uhi += 0x7fffu + ((uhi >> 16) & 1u);
    return (ulo >> 16) | (uhi & 0xffff0000u);
}

// ---------------- WA[l][k][j] = sum_c W[l][k][c] * A[c][j] ----------------
// A[c][2h]=att_src[l][c] (c in head h), A[c][2h+1]=att_dst[l][c]. grid = 2*96 blocks x 64.
__global__ void wa_kernel(const float* __restrict__ W, const float* __restrict__ att_src,
                          const float* __restrict__ att_dst, float* __restrict__ wa) {
    const int l = blockIdx.x / DD;
    const int k = blockIdx.x % DD;
    const int t = threadIdx.x;          // 0..63
    const float* Wr = W + ((size_t)l * DD + k) * HD;
    const float* as = att_src + (size_t)l * HD;
    const float* ad = att_dst + (size_t)l * HD;
    const bool hiHalf = t >= 32;
    float s0=0,s1=0,s2=0,s3=0,d0=0,d1=0,d2=0,d3=0;
    int c; float w, ps, pd;
    c = t;       w = Wr[c]; s0 = fmaf(w, as[c], s0); d0 = fmaf(w, ad[c], d0);
    c = t + 64;  w = Wr[c]; ps = w * as[c]; pd = w * ad[c];
    s0 += hiHalf ? 0.f : ps;  s1 += hiHalf ? ps : 0.f;
    d0 += hiHalf ? 0.f : pd;  d1 += hiHalf ? pd : 0.f;
    c = t + 128; w = Wr[c]; s1 = fmaf(w, as[c], s1); d1 = fmaf(w, ad[c], d1);
    c = t + 192; w = Wr[c]; s2 = fmaf(w, as[c], s2); d2 = fmaf(w, ad[c], d2);
    c = t + 256; w = Wr[c]; ps = w * as[c]; pd = w * ad[c];
    s2 += hiHalf ? 0.f : ps;  s3 += hiHalf ? ps : 0.f;
    d2 += hiHalf ? 0.f : pd;  d3 += hiHalf ? pd : 0.f;
    c = t + 320; w = Wr[c]; s3 = fmaf(w, as[c], s3); d3 = fmaf(w, ad[c], d3);
#pragma unroll
    for (int off = 32; off; off >>= 1) {
        s0 += __shfl_xor(s0, off); s1 += __shfl_xor(s1, off);
        s2 += __shfl_xor(s2, off); s3 += __shfl_xor(s3, off);
        d0 += __shfl_xor(d0, off); d1 += __shfl_xor(d1, off);
        d2 += __shfl_xor(d2, off); d3 += __shfl_xor(d3, off);
    }
    if (t == 0) {
        float* o = wa + ((size_t)l * DD + k) * 8;
        o[0]=s0; o[1]=d0; o[2]=s1; o[3]=d1; o[4]=s2; o[5]=d2; o[6]=s3; o[7]=d3;
    }
}

// ---------------- GEMM + fused alpha: 256 thr, 32 nodes; lane owns cols l+64j ---------
// hp layout: uint plane j at hp[n*192 + j*64 + lane] = pack(col l+128j? see pairing):
//   u0=(c_l, c_{l+64}), u1=(c_{l+128}, c_{l+192}), u2=(c_{l+256}, c_{l+320})
__global__ void __launch_bounds__(256) gemm_kernel(const float* __restrict__ x,
        const float* __restrict__ W, const float* __restrict__ wa,
        uint* __restrict__ hp, float* __restrict__ asrc, float* __restrict__ adst, int N) {
    __shared__ float xs[GN * 100];      // stride 100 breaks bank aliasing for alpha reads
    __shared__ float was[DD * 8];
    const int t = threadIdx.x;
    const int n0 = blockIdx.x * GN;
    const int nvalid = min(GN, N - n0);

    for (int i = t; i < DD * 8; i += 256) was[i] = wa[i];
    {
        const float4* xsrc = (const float4*)(x + (size_t)n0 * DD);
        const int lim = (nvalid * DD) / 4;
        for (int i4 = t; i4 < lim; i4 += 256) {
            const float4 v = xsrc[i4];
            const int node = i4 / 24, k = (i4 % 24) * 4;
            float* dp = &xs[node * 100 + k];
            dp[0] = v.x; dp[1] = v.y; dp[2] = v.z; dp[3] = v.w;
        }
    }
    __syncthreads();

    const int lane = t & 63;
    const int nb = (t >> 6) * 8;        // first node of this wave
    float acc[8][6];
#pragma unroll
    for (int nn = 0; nn < 8; nn++)
#pragma unroll
        for (int j = 0; j < 6; j++) acc[nn][j] = 0.f;

    for (int k = 0; k < DD; k++) {
        float wv[6];
#pragma unroll
        for (int j = 0; j < 6; j++) wv[j] = W[(size_t)k * HD + j * 64 + lane];
#pragma unroll
        for (int nn = 0; nn < 8; nn++) {
            const float xv = xs[(nb + nn) * 100 + k];
#pragma unroll
            for (int j = 0; j < 6; j++) acc[nn][j] = fmaf(xv, wv[j], acc[nn][j]);
        }
    }
#pragma unroll
    for (int nn = 0; nn < 8; nn++) {
        if (nb + nn < nvalid) {
            uint* hr = hp + (size_t)(n0 + nb + nn) * 192;
            hr[lane]       = pack2bf(acc[nn][0], acc[nn][1]);
            hr[64 + lane]  = pack2bf(acc[nn][2], acc[nn][3]);
            hr[128 + lane] = pack2bf(acc[nn][4], acc[nn][5]);
        }
    }
    // fused alpha: thread t -> (node t>>3, output j=t&7); alpha = x-row . WA[:,j]
    {
        const int nn = t >> 3, j = t & 7;
        if (nn < nvalid) {
            const float* xr = &xs[nn * 100];
            float s = 0.f;
            for (int k = 0; k < DD; k++) s = fmaf(xr[k], was[k * 8 + j], s);
            const int n = n0 + nn, h = j >> 1;
            if ((j & 1) == 0) asrc[n * 4 + h] = s;
            else              adst[n * 4 + h] = s;
        }
    }
}

// ---------------- CSR build ----------------
__global__ void count_kernel(const int* __restrict__ ei, int* __restrict__ deg, int E) {
    int i = blockIdx.x * blockDim.x + threadIdx.x;
    const int stride = gridDim.x * blockDim.x;
    for (; i < E; i += stride) atomicAdd(&deg[ei[E + i]], 1);
}

// exclusive scan of (deg[i]+1) -> rowptr & cursor (self-loop folded in)
__global__ void scan_kernel(const int* __restrict__ deg, int* __restrict__ rowptr,
                            int* __restrict__ cursor, int N) {
    __shared__ int lsum[1024];
    const int t = threadIdx.x;
    const int per = (N + 1023) / 1024;
    const int start = t * per;
    const int end = min(start + per, N);
    int s = 0;
    for (int i = start; i < end; i++) s += deg[i] + 1;
    lsum[t] = s;
    __syncthreads();
    for (int off = 1; off < 1024; off <<= 1) {
        int u = (t >= off) ? lsum[t - off] : 0;
        __syncthreads();
        lsum[t] += u;
        __syncthreads();
    }
    int run = lsum[t] - s;
    for (int i = start; i < end; i++) {
        rowptr[i] = run; cursor[i] = run;
        run += deg[i] + 1;
    }
    if (t == 1023) rowptr[N] = lsum[1023];
}

__global__ void scatter_kernel(const int* __restrict__ ei, int* __restrict__ cursor,
                               const int* __restrict__ rowptr, int* __restrict__ col,
                               int E, int Etot) {
    int i = blockIdx.x * blockDim.x + threadIdx.x;
    const int stride = gridDim.x * blockDim.x;
    for (; i < Etot; i += stride) {
        if (i < E) {
            const int src = ei[i], dst = ei[E + i];
            col[atomicAdd(&cursor[dst], 1)] = src;
        } else {
            const int n = i - E;
            col[rowptr[n + 1] - 1] = n;     // self-loop slot, non-atomic
        }
    }
}

// ---------------- fused aggregate (packed h, 2-edge unrolled) ----------------
#define EDGE_W(av, w0, w1, w2, w3, cf1, cf4)                                          \
    { float t0 = av.x + adv.x, t1 = av.y + adv.y, t2 = av.z + adv.z, t3 = av.w + adv.w; \
      t0 = t0 > 0.f ? t0 : NEG_SLOPE * t0;  t1 = t1 > 0.f ? t1 : NEG_SLOPE * t1;      \
      t2 = t2 > 0.f ? t2 : NEG_SLOPE * t2;  t3 = t3 > 0.f ? t3 : NEG_SLOPE * t3;      \
      w0 = __expf(t0); w1 = __expf(t1); w2 = __expf(t2); w3 = __expf(t3);             \
      den0 += w0; den1 += w1; den2 += w2; den3 += w3;                                 \
      cf1 = hi32 ? w1 : w0; cf4 = hi32 ? w3 : w2; }

#define EDGE_FMA(u0, u1, u2, w0, w1, w2, w3, cf1, cf4)                                \
    { acc0 = fmaf(__uint_as_float(u0 << 16), w0, acc0);                               \
      acc1 = fmaf(__uint_as_float(u0 & 0xffff0000u), cf1, acc1);                      \
      acc2 = fmaf(__uint_as_float(u1 << 16), w1, acc2);                               \
      acc3 = fmaf(__uint_as_float(u1 & 0xffff0000u), w2, acc3);                       \
      acc4 = fmaf(__uint_as_float(u2 << 16), cf4, acc4);                              \
      acc5 = fmaf(__uint_as_float(u2 & 0xffff0000u), w3, acc5); }

__global__ void agg_csr_kernel(const int* __restrict__ rowptr, const int* __restrict__ col,
                               const uint* __restrict__ hp, const float* __restrict__ asrc,
                               const float* __restrict__ adst, const float* __restrict__ bias,
                               float* __restrict__ y, int N) {
    const int lane = threadIdx.x & 63;
    const bool hi32 = lane >= 32;
    const int n = (blockIdx.x * blockDim.x + threadIdx.x) >> 6;
    if (n >= N) return;
    const int beg = rowptr[n], endp = rowptr[n + 1];
    const float4 adv = *(const float4*)(adst + (size_t)n * 4);
    float acc0=0,acc1=0,acc2=0,acc3=0,acc4=0,acc5=0;
    float den0=0,den1=0,den2=0,den3=0;
    int e = beg;
    for (; e + 2 <= endp; e += 2) {
        const int s0 = col[e], s1 = col[e + 1];
        const float4 av0 = *(const float4*)(asrc + (size_t)s0 * 4);
        const float4 av1 = *(const float4*)(asrc + (size_t)s1 * 4);
        const uint* h0 = hp + (size_t)s0 * 192 + lane;
        const uint* h1 = hp + (size_t)s1 * 192 + lane;
        const uint u00 = h0[0], u01 = h0[64], u02 = h0[128];
        const uint u10 = h1[0], u11 = h1[64], u12 = h1[128];
        float w0,w1,w2,w3,cf1,cf4;
        EDGE_W(av0, w0, w1, w2, w3, cf1, cf4);
        EDGE_FMA(u00, u01, u02, w0, w1, w2, w3, cf1, cf4);
        EDGE_W(av1, w0, w1, w2, w3, cf1, cf4);
        EDGE_FMA(u10, u11, u12, w0, w1, w2, w3, cf1, cf4);
    }
    if (e < endp) {
        const int s0 = col[e];
        const float4 av0 = *(const float4*)(asrc + (size_t)s0 * 4);
        const uint* h0 = hp + (size_t)s0 * 192 + lane;
        const uint u00 = h0[0], u01 = h0[64], u02 = h0[128];
        float w0,w1,w2,w3,cf1,cf4;
        EDGE_W(av0, w0, w1, w2, w3, cf1, cf4);
        EDGE_FMA(u00, u01, u02, w0, w1, w2, w3, cf1, cf4);
    }
    const float r0 = 1.f / (den0 + 1e-16f);
    const float r1 = 1.f / (den1 + 1e-16f);
    const float r2 = 1.f / (den2 + 1e-16f);
    const float r3 = 1.f / (den3 + 1e-16f);
    const float rc1 = hi32 ? r1 : r0;
    const float rc4 = hi32 ? r3 : r2;
    const float A = acc0 * r0  + acc3 * r2;
    const float B = acc1 * rc1 + acc4 * rc4;
    const float C = acc2 * r1  + acc5 * r3;
    const float shB = __shfl_xor(B, 32);
    const float shC = __shfl_xor(C, 32);
    float* yr = y + (size_t)n * DD;
    yr[lane] = 0.25f * (A + (hi32 ? shC : shB)) + bias[lane];
    if (!hi32) yr[64 + lane] = 0.25f * (B + shC) + bias[64 + lane];
}

// ---------------- BN stats: deterministic block partials ----------------
__global__ void bnstats_kernel(const float* __restrict__ y, float* __restrict__ pbuf,
                               int total4) {
    __shared__ float ps[384 * 4];
    __shared__ float qs[384 * 4];
    const int t = threadIdx.x;          // 0..383
    const int stride = gridDim.x * 384;
    float s0=0,s1=0,s2=0,s3=0,q0=0,q1=0,q2=0,q3=0;
    for (int i = blockIdx.x * 384 + t; i < total4; i += stride) {
        const float4 v = ((const float4*)y)[i];
        s0 += v.x; q0 = fmaf(v.x, v.x, q0);
        s1 += v.y; q1 = fmaf(v.y, v.y, q1);
        s2 += v.z; q2 = fmaf(v.z, v.z, q2);
        s3 += v.w; q3 = fmaf(v.w, v.w, q3);
    }
    ps[t*4+0]=s0; ps[t*4+1]=s1; ps[t*4+2]=s2; ps[t*4+3]=s3;
    qs[t*4+0]=q0; qs[t*4+1]=q1; qs[t*4+2]=q2; qs[t*4+3]=q3;
    __syncthreads();
    // feature d gathers flat LDS indices d + 96*m, m=0..15
    if (t < 192) {
        const int d = t % 96;
        const float* src = (t < 96) ? ps : qs;
        float r = 0.f;
#pragma unroll
        for (int m = 0; m < 16; m++) r += src[d + 96 * m];
        pbuf[blockIdx.x * 192 + t] = r;
    }
}

__global__ void bnfin_kernel(const float* __restrict__ pbuf, const float* __restrict__ gamma,
                             const float* __restrict__ beta, float* __restrict__ scsh, int N) {
    const int d = threadIdx.x;   // 96
    float s = 0.f, q = 0.f;
    for (int b = 0; b < NB_STATS; b++) {
        s += pbuf[b * 192 + d];
        q += pbuf[b * 192 + 96 + d];
    }
    const float invN = 1.f / (float)N;
    const float mu = s * invN;
    const float var = q * invN - mu * mu;
    const float sc = gamma[d] * rsqrtf(var + 1e-5f);
    scsh[d] = sc;
    scsh[d + DD] = beta[d] - mu * sc;
}

__global__ void bn_apply_kernel(const float* __restrict__ y, const float* __restrict__ scsh,
                                const float* __restrict__ xin, float* __restrict__ xout,
                                int total4) {
    int i = blockIdx.x * blockDim.x + threadIdx.x;
    const int stride = gridDim.x * blockDim.x;
    for (; i < total4; i += stride) {
        const int d4 = (i % 24) * 4;
        const float4 v = ((const float4*)y)[i];
        const float4 xi = ((const float4*)xin)[i];
        float4 o; float a;
        a = fmaf(v.x, scsh[d4],     scsh[d4 + DD]);     o.x = (a > 0.f ? a : 0.f) + xi.x;
        a = fmaf(v.y, scsh[d4 + 1], scsh[d4 + 1 + DD]); o.y = (a > 0.f ? a : 0.f) + xi.y;
        a = fmaf(v.z, scsh[d4 + 2], scsh[d4 + 2 + DD]); o.z = (a > 0.f ? a : 0.f) + xi.z;
        a = fmaf(v.w, scsh[d4 + 3], scsh[d4 + 3 + DD]); o.w = (a > 0.f ? a : 0.f) + xi.w;
        ((float4*)xout)[i] = o;
    }
}

extern "C" void kernel_launch(void* const* d_in, const int* in_sizes, int n_in,
                              void* d_out, int out_size, void* d_ws, size_t ws_size,
                              hipStream_t stream) {
    const float* x        = (const float*)d_in[0];
    const int*   ei       = (const int*)d_in[1];
    const float* W        = (const float*)d_in[2];
    const float* att_src  = (const float*)d_in[3];
    const float* att_dst  = (const float*)d_in[4];
    const float* bias     = (const float*)d_in[5];
    const float* gamma    = (const float*)d_in[6];
    const float* beta     = (const float*)d_in[7];
    float* out_final = (float*)d_out;

    const int N = in_sizes[0] / DD;     // 50000
    const int E = in_sizes[1] / 2;      // 800000
    const int Etot = E + N;

    char* ws = (char*)d_ws;
    size_t off = 0;
    auto alloc = [&](size_t bytes) -> void* {
        void* p = ws + off;
        off += (bytes + 255) & ~(size_t)255;
        return p;
    };
    uint*  hp     = (uint*)alloc((size_t)N * 192 * 4);
    float* asrc   = (float*)alloc((size_t)N * HH * 4);
    float* adst   = (float*)alloc((size_t)N * HH * 4);
    float* y      = (float*)alloc((size_t)N * DD * 4);
    float* xbuf   = (float*)alloc((size_t)N * DD * 4);
    float* pbuf   = (float*)alloc((size_t)NB_STATS * 192 * 4);
    float* scsh   = (float*)alloc(2 * DD * 4);
    float* wa     = (float*)alloc(2 * DD * 8 * 4);
    int*   deg    = (int*)alloc((size_t)N * 4);
    int*   rowptr = (int*)alloc((size_t)(N + 1) * 4);
    int*   cursor = (int*)alloc((size_t)N * 4);
    int*   colidx = (int*)alloc((size_t)Etot * 4);

    // ---- CSR by destination + WA precompute (layer-invariant structure) ----
    hipMemsetAsync(deg, 0, (size_t)N * 4, stream);
    count_kernel<<<1024, 256, 0, stream>>>(ei, deg, E);
    scan_kernel<<<1, 1024, 0, stream>>>(deg, rowptr, cursor, N);
    scatter_kernel<<<1024, 256, 0, stream>>>(ei, cursor, rowptr, colidx, E, Etot);
    wa_kernel<<<2 * DD, 64, 0, stream>>>(W, att_src, att_dst, wa);

    for (int l = 0; l < 2; l++) {
        const float* xin = (l == 0) ? x : xbuf;
        float* xout = (l == 1) ? out_final : xbuf;

        gemm_kernel<<<(N + GN - 1) / GN, 256, 0, stream>>>(
            xin, W + (size_t)l * DD * HD, wa + (size_t)l * DD * 8, hp, asrc, adst, N);
        agg_csr_kernel<<<(N * 64 + 255) / 256, 256, 0, stream>>>(
            rowptr, colidx, hp, asrc, adst, bias + (size_t)l * DD, y, N);
        bnstats_kernel<<<NB_STATS, 384, 0, stream>>>(y, pbuf, N * DD / 4);
        bnfin_kernel<<<1, DD, 0, stream>>>(pbuf, gamma + (size_t)l * DD,
                                           beta + (size_t)l * DD, scsh, N);
        bn_apply_kernel<<<2048, 256, 0, stream>>>(y, scsh, xin, xout, N * DD / 4);
    }
}

// Round 5
// 469.899 us; speedup vs baseline: 5.8311x; 1.2111x over previous
//
#include <hip/hip_runtime.h>

#define DD 96
#define HH 4
#define HD 384
#define GN 32            // nodes per gemm block
#define NEG_SLOPE 0.2f
#define NB_STATS 128     // bnstats blocks
#define SCAN_BS 1024     // elements per scan block

typedef unsigned int uint;
typedef unsigned short ushort;

__device__ inline uint pack2bf(float lo, float hi) {   // round-to-nearest-even both halves
    uint ulo = __float_as_uint(lo); ulo += 0x7fffu + ((ulo >> 16) & 1u);
    uint uhi = __float_as_uint(hi); uhi += 0x7fffu + ((uhi >> 16) & 1u);
    return (ulo >> 16) | (uhi & 0xffff0000u);
}

// ---------------- WA[l][k][j] = sum_c W[l][k][c] * A[c][j] ----------------
__global__ void wa_kernel(const float* __restrict__ W, const float* __restrict__ att_src,
                          const float* __restrict__ att_dst, float* __restrict__ wa) {
    const int l = blockIdx.x / DD;
    const int k = blockIdx.x % DD;
    const int t = threadIdx.x;          // 0..63
    const float* Wr = W + ((size_t)l * DD + k) * HD;
    const float* as = att_src + (size_t)l * HD;
    const float* ad = att_dst + (size_t)l * HD;
    const bool hiHalf = t >= 32;
    float s0=0,s1=0,s2=0,s3=0,d0=0,d1=0,d2=0,d3=0;
    int c; float w, ps, pd;
    c = t;       w = Wr[c]; s0 = fmaf(w, as[c], s0); d0 = fmaf(w, ad[c], d0);
    c = t + 64;  w = Wr[c]; ps = w * as[c]; pd = w * ad[c];
    s0 += hiHalf ? 0.f : ps;  s1 += hiHalf ? ps : 0.f;
    d0 += hiHalf ? 0.f : pd;  d1 += hiHalf ? pd : 0.f;
    c = t + 128; w = Wr[c]; s1 = fmaf(w, as[c], s1); d1 = fmaf(w, ad[c], d1);
    c = t + 192; w = Wr[c]; s2 = fmaf(w, as[c], s2); d2 = fmaf(w, ad[c], d2);
    c = t + 256; w = Wr[c]; ps = w * as[c]; pd = w * ad[c];
    s2 += hiHalf ? 0.f : ps;  s3 += hiHalf ? ps : 0.f;
    d2 += hiHalf ? 0.f : pd;  d3 += hiHalf ? pd : 0.f;
    c = t + 320; w = Wr[c]; s3 = fmaf(w, as[c], s3); d3 = fmaf(w, ad[c], d3);
#pragma unroll
    for (int off = 32; off; off >>= 1) {
        s0 += __shfl_xor(s0, off); s1 += __shfl_xor(s1, off);
        s2 += __shfl_xor(s2, off); s3 += __shfl_xor(s3, off);
        d0 += __shfl_xor(d0, off); d1 += __shfl_xor(d1, off);
        d2 += __shfl_xor(d2, off); d3 += __shfl_xor(d3, off);
    }
    if (t == 0) {
        float* o = wa + ((size_t)l * DD + k) * 8;
        o[0]=s0; o[1]=d0; o[2]=s1; o[3]=d1; o[4]=s2; o[5]=d2; o[6]=s3; o[7]=d3;
    }
}

// ---------------- GEMM + fused alpha ----------------
__global__ void __launch_bounds__(256) gemm_kernel(const float* __restrict__ x,
        const float* __restrict__ W, const float* __restrict__ wa,
        uint* __restrict__ hp, float* __restrict__ asrc, float* __restrict__ adst, int N) {
    __shared__ float xs[GN * 100];
    __shared__ float was[DD * 8];
    const int t = threadIdx.x;
    const int n0 = blockIdx.x * GN;
    const int nvalid = min(GN, N - n0);

    for (int i = t; i < DD * 8; i += 256) was[i] = wa[i];
    {
        const float4* xsrc = (const float4*)(x + (size_t)n0 * DD);
        const int lim = (nvalid * DD) / 4;
        for (int i4 = t; i4 < lim; i4 += 256) {
            const float4 v = xsrc[i4];
            const int node = i4 / 24, k = (i4 % 24) * 4;
            float* dp = &xs[node * 100 + k];
            dp[0] = v.x; dp[1] = v.y; dp[2] = v.z; dp[3] = v.w;
        }
    }
    __syncthreads();

    const int lane = t & 63;
    const int nb = (t >> 6) * 8;
    float acc[8][6];
#pragma unroll
    for (int nn = 0; nn < 8; nn++)
#pragma unroll
        for (int j = 0; j < 6; j++) acc[nn][j] = 0.f;

    for (int k = 0; k < DD; k++) {
        float wv[6];
#pragma unroll
        for (int j = 0; j < 6; j++) wv[j] = W[(size_t)k * HD + j * 64 + lane];
#pragma unroll
        for (int nn = 0; nn < 8; nn++) {
            const float xv = xs[(nb + nn) * 100 + k];
#pragma unroll
            for (int j = 0; j < 6; j++) acc[nn][j] = fmaf(xv, wv[j], acc[nn][j]);
        }
    }
#pragma unroll
    for (int nn = 0; nn < 8; nn++) {
        if (nb + nn < nvalid) {
            uint* hr = hp + (size_t)(n0 + nb + nn) * 192;
            hr[lane]       = pack2bf(acc[nn][0], acc[nn][1]);
            hr[64 + lane]  = pack2bf(acc[nn][2], acc[nn][3]);
            hr[128 + lane] = pack2bf(acc[nn][4], acc[nn][5]);
        }
    }
    {
        const int nn = t >> 3, j = t & 7;
        if (nn < nvalid) {
            const float* xr = &xs[nn * 100];
            float s = 0.f;
            for (int k = 0; k < DD; k++) s = fmaf(xr[k], was[k * 8 + j], s);
            const int n = n0 + nn, h = j >> 1;
            if ((j & 1) == 0) asrc[n * 4 + h] = s;
            else              adst[n * 4 + h] = s;
        }
    }
}

// ---------------- CSR build ----------------
__global__ void count_kernel(const int* __restrict__ ei, int* __restrict__ deg, int E) {
    int i = blockIdx.x * blockDim.x + threadIdx.x;
    const int stride = gridDim.x * blockDim.x;
    for (; i < E; i += stride) atomicAdd(&deg[ei[E + i]], 1);
}

// phase 1: per-block local exclusive prefixes of (deg[i]+1) + block totals
__global__ void scan1_kernel(const int* __restrict__ deg, int* __restrict__ locpre,
                             int* __restrict__ bsum, int N) {
    __shared__ int ts[256];
    const int t = threadIdx.x;
    const int base = blockIdx.x * SCAN_BS + t * 4;
    int e0 = 0, e1 = 0, e2 = 0, e3 = 0;
    if (base + 3 < N) {
        const int4 v = *(const int4*)(deg + base);
        e0 = v.x + 1; e1 = v.y + 1; e2 = v.z + 1; e3 = v.w + 1;
    } else {
        if (base     < N) e0 = deg[base]     + 1;
        if (base + 1 < N) e1 = deg[base + 1] + 1;
        if (base + 2 < N) e2 = deg[base + 2] + 1;
        if (base + 3 < N) e3 = deg[base + 3] + 1;
    }
    const int s = e0 + e1 + e2 + e3;
    ts[t] = s;
    __syncthreads();
    for (int off = 1; off < 256; off <<= 1) {
        const int u = (t >= off) ? ts[t - off] : 0;
        __syncthreads();
        ts[t] += u;
        __syncthreads();
    }
    const int ex = ts[t] - s;
    if (base + 3 < N) {
        *(int4*)(locpre + base) = make_int4(ex, ex + e0, ex + e0 + e1, ex + e0 + e1 + e2);
    } else if (base < N) {
        locpre[base] = ex;
        if (base + 1 < N) locpre[base + 1] = ex + e0;
        if (base + 2 < N) locpre[base + 2] = ex + e0 + e1;
    }
    if (t == 255) bsum[blockIdx.x] = ts[255];
}

// phase 2: one wave exclusive-scans block totals (NBLK <= 64), writes rowptr[N]
__global__ void scan2_kernel(int* __restrict__ bsum, int* __restrict__ rowptr,
                             int NBLK, int N) {
    const int t = threadIdx.x;          // 0..63
    const int mine = (t < NBLK) ? bsum[t] : 0;
    int v = mine;
#pragma unroll
    for (int off = 1; off < 64; off <<= 1) {
        const int u = __shfl_up(v, off);
        if (t >= off) v += u;
    }
    if (t < NBLK) bsum[t] = v - mine;   // exclusive
    if (t == 63) rowptr[N] = v;         // grand total
}

// phase 3: add block offsets, emit rowptr & cursor
__global__ void scan3_kernel(const int* __restrict__ locpre, const int* __restrict__ bsum,
                             int* __restrict__ rowptr, int* __restrict__ cursor, int N) {
    const int base = blockIdx.x * SCAN_BS + threadIdx.x * 4;
    const int boff = bsum[blockIdx.x];
    if (base + 3 < N) {
        int4 v = *(const int4*)(locpre + base);
        v.x += boff; v.y += boff; v.z += boff; v.w += boff;
        *(int4*)(rowptr + base) = v;
        *(int4*)(cursor + base) = v;
    } else {
        for (int i = base; i < N; i++) {
            const int r = locpre[i] + boff;
            rowptr[i] = r; cursor[i] = r;
        }
    }
}

__global__ void scatter_kernel(const int* __restrict__ ei, int* __restrict__ cursor,
                               const int* __restrict__ rowptr, int* __restrict__ col,
                               int E, int Etot) {
    int i = blockIdx.x * blockDim.x + threadIdx.x;
    const int stride = gridDim.x * blockDim.x;
    for (; i < Etot; i += stride) {
        if (i < E) {
            const int src = ei[i], dst = ei[E + i];
            col[atomicAdd(&cursor[dst], 1)] = src;
        } else {
            const int n = i - E;
            col[rowptr[n + 1] - 1] = n;     // self-loop slot, non-atomic
        }
    }
}

// ---------------- fused aggregate (packed h, 4-edge unrolled) ----------------
#define EDGE_W(av, w0, w1, w2, w3, cf1, cf4)                                          \
    { float t0 = av.x + adv.x, t1 = av.y + adv.y, t2 = av.z + adv.z, t3 = av.w + adv.w; \
      t0 = t0 > 0.f ? t0 : NEG_SLOPE * t0;  t1 = t1 > 0.f ? t1 : NEG_SLOPE * t1;      \
      t2 = t2 > 0.f ? t2 : NEG_SLOPE * t2;  t3 = t3 > 0.f ? t3 : NEG_SLOPE * t3;      \
      w0 = __expf(t0); w1 = __expf(t1); w2 = __expf(t2); w3 = __expf(t3);             \
      den0 += w0; den1 += w1; den2 += w2; den3 += w3;                                 \
      cf1 = hi32 ? w1 : w0; cf4 = hi32 ? w3 : w2; }

#define EDGE_FMA(u0, u1, u2, w0, w1, w2, w3, cf1, cf4)                                \
    { acc0 = fmaf(__uint_as_float(u0 << 16), w0, acc0);                               \
      acc1 = fmaf(__uint_as_float(u0 & 0xffff0000u), cf1, acc1);                      \
      acc2 = fmaf(__uint_as_float(u1 << 16), w1, acc2);                               \
      acc3 = fmaf(__uint_as_float(u1 & 0xffff0000u), w2, acc3);                       \
      acc4 = fmaf(__uint_as_float(u2 << 16), cf4, acc4);                              \
      acc5 = fmaf(__uint_as_float(u2 & 0xffff0000u), w3, acc5); }

__global__ void agg_csr_kernel(const int* __restrict__ rowptr, const int* __restrict__ col,
                               const uint* __restrict__ hp, const float* __restrict__ asrc,
                               const float* __restrict__ adst, const float* __restrict__ bias,
                               float* __restrict__ y, int N) {
    const int lane = threadIdx.x & 63;
    const bool hi32 = lane >= 32;
    const int n = (blockIdx.x * blockDim.x + threadIdx.x) >> 6;
    if (n >= N) return;
    const int beg = rowptr[n], endp = rowptr[n + 1];
    const float4 adv = *(const float4*)(adst + (size_t)n * 4);
    float acc0=0,acc1=0,acc2=0,acc3=0,acc4=0,acc5=0;
    float den0=0,den1=0,den2=0,den3=0;
    int e = beg;
    for (; e + 4 <= endp; e += 4) {
        const int s0 = col[e], s1 = col[e + 1], s2 = col[e + 2], s3 = col[e + 3];
        const float4 av0 = *(const float4*)(asrc + (size_t)s0 * 4);
        const float4 av1 = *(const float4*)(asrc + (size_t)s1 * 4);
        const float4 av2 = *(const float4*)(asrc + (size_t)s2 * 4);
        const float4 av3 = *(const float4*)(asrc + (size_t)s3 * 4);
        const uint* h0 = hp + (size_t)s0 * 192 + lane;
        const uint* h1 = hp + (size_t)s1 * 192 + lane;
        const uint* h2 = hp + (size_t)s2 * 192 + lane;
        const uint* h3 = hp + (size_t)s3 * 192 + lane;
        const uint u00 = h0[0], u01 = h0[64], u02 = h0[128];
        const uint u10 = h1[0], u11 = h1[64], u12 = h1[128];
        const uint u20 = h2[0], u21 = h2[64], u22 = h2[128];
        const uint u30 = h3[0], u31 = h3[64], u32 = h3[128];
        float w0,w1,w2,w3,cf1,cf4;
        EDGE_W(av0, w0, w1, w2, w3, cf1, cf4);
        EDGE_FMA(u00, u01, u02, w0, w1, w2, w3, cf1, cf4);
        EDGE_W(av1, w0, w1, w2, w3, cf1, cf4);
        EDGE_FMA(u10, u11, u12, w0, w1, w2, w3, cf1, cf4);
        EDGE_W(av2, w0, w1, w2, w3, cf1, cf4);
        EDGE_FMA(u20, u21, u22, w0, w1, w2, w3, cf1, cf4);
        EDGE_W(av3, w0, w1, w2, w3, cf1, cf4);
        EDGE_FMA(u30, u31, u32, w0, w1, w2, w3, cf1, cf4);
    }
    for (; e < endp; e++) {
        const int s0 = col[e];
        const float4 av0 = *(const float4*)(asrc + (size_t)s0 * 4);
        const uint* h0 = hp + (size_t)s0 * 192 + lane;
        const uint u00 = h0[0], u01 = h0[64], u02 = h0[128];
        float w0,w1,w2,w3,cf1,cf4;
        EDGE_W(av0, w0, w1, w2, w3, cf1, cf4);
        EDGE_FMA(u00, u01, u02, w0, w1, w2, w3, cf1, cf4);
    }
    const float r0 = 1.f / (den0 + 1e-16f);
    const float r1 = 1.f / (den1 + 1e-16f);
    const float r2 = 1.f / (den2 + 1e-16f);
    const float r3 = 1.f / (den3 + 1e-16f);
    const float rc1 = hi32 ? r1 : r0;
    const float rc4 = hi32 ? r3 : r2;
    const float A = acc0 * r0  + acc3 * r2;
    const float B = acc1 * rc1 + acc4 * rc4;
    const float C = acc2 * r1  + acc5 * r3;
    const float shB = __shfl_xor(B, 32);
    const float shC = __shfl_xor(C, 32);
    float* yr = y + (size_t)n * DD;
    yr[lane] = 0.25f * (A + (hi32 ? shC : shB)) + bias[lane];
    if (!hi32) yr[64 + lane] = 0.25f * (B + shC) + bias[64 + lane];
}

// ---------------- BN stats: deterministic block partials ----------------
__global__ void bnstats_kernel(const float* __restrict__ y, float* __restrict__ pbuf,
                               int total4) {
    __shared__ float ps[384 * 4];
    __shared__ float qs[384 * 4];
    const int t = threadIdx.x;          // 0..383
    const int stride = gridDim.x * 384;
    float s0=0,s1=0,s2=0,s3=0,q0=0,q1=0,q2=0,q3=0;
    for (int i = blockIdx.x * 384 + t; i < total4; i += stride) {
        const float4 v = ((const float4*)y)[i];
        s0 += v.x; q0 = fmaf(v.x, v.x, q0);
        s1 += v.y; q1 = fmaf(v.y, v.y, q1);
        s2 += v.z; q2 = fmaf(v.z, v.z, q2);
        s3 += v.w; q3 = fmaf(v.w, v.w, q3);
    }
    ps[t*4+0]=s0; ps[t*4+1]=s1; ps[t*4+2]=s2; ps[t*4+3]=s3;
    qs[t*4+0]=q0; qs[t*4+1]=q1; qs[t*4+2]=q2; qs[t*4+3]=q3;
    __syncthreads();
    if (t < 192) {
        const int d = t % 96;
        const float* src = (t < 96) ? ps : qs;
        float r = 0.f;
#pragma unroll
        for (int m = 0; m < 16; m++) r += src[d + 96 * m];
        pbuf[blockIdx.x * 192 + t] = r;
    }
}

__global__ void bnfin_kernel(const float* __restrict__ pbuf, const float* __restrict__ gamma,
                             const float* __restrict__ beta, float* __restrict__ scsh, int N) {
    const int d = threadIdx.x;   // 96
    float s = 0.f, q = 0.f;
    for (int b = 0; b < NB_STATS; b++) {
        s += pbuf[b * 192 + d];
        q += pbuf[b * 192 + 96 + d];
    }
    const float invN = 1.f / (float)N;
    const float mu = s * invN;
    const float var = q * invN - mu * mu;
    const float sc = gamma[d] * rsqrtf(var + 1e-5f);
    scsh[d] = sc;
    scsh[d + DD] = beta[d] - mu * sc;
}

__global__ void bn_apply_kernel(const float* __restrict__ y, const float* __restrict__ scsh,
                                const float* __restrict__ xin, float* __restrict__ xout,
                                int total4) {
    int i = blockIdx.x * blockDim.x + threadIdx.x;
    const int stride = gridDim.x * blockDim.x;
    for (; i < total4; i += stride) {
        const int d4 = (i % 24) * 4;
        const float4 v = ((const float4*)y)[i];
        const float4 xi = ((const float4*)xin)[i];
        float4 o; float a;
        a = fmaf(v.x, scsh[d4],     scsh[d4 + DD]);     o.x = (a > 0.f ? a : 0.f) + xi.x;
        a = fmaf(v.y, scsh[d4 + 1], scsh[d4 + 1 + DD]); o.y = (a > 0.f ? a : 0.f) + xi.y;
        a = fmaf(v.z, scsh[d4 + 2], scsh[d4 + 2 + DD]); o.z = (a > 0.f ? a : 0.f) + xi.z;
        a = fmaf(v.w, scsh[d4 + 3], scsh[d4 + 3 + DD]); o.w = (a > 0.f ? a : 0.f) + xi.w;
        ((float4*)xout)[i] = o;
    }
}

extern "C" void kernel_launch(void* const* d_in, const int* in_sizes, int n_in,
                              void* d_out, int out_size, void* d_ws, size_t ws_size,
                              hipStream_t stream) {
    const float* x        = (const float*)d_in[0];
    const int*   ei       = (const int*)d_in[1];
    const float* W        = (const float*)d_in[2];
    const float* att_src  = (const float*)d_in[3];
    const float* att_dst  = (const float*)d_in[4];
    const float* bias     = (const float*)d_in[5];
    const float* gamma    = (const float*)d_in[6];
    const float* beta     = (const float*)d_in[7];
    float* out_final = (float*)d_out;

    const int N = in_sizes[0] / DD;     // 50000
    const int E = in_sizes[1] / 2;      // 800000
    const int Etot = E + N;
    const int NBLK = (N + SCAN_BS - 1) / SCAN_BS;   // 49 (must be <= 64)

    char* ws = (char*)d_ws;
    size_t off = 0;
    auto alloc = [&](size_t bytes) -> void* {
        void* p = ws + off;
        off += (bytes + 255) & ~(size_t)255;
        return p;
    };
    uint*  hp     = (uint*)alloc((size_t)N * 192 * 4);
    float* asrc   = (float*)alloc((size_t)N * HH * 4);
    float* adst   = (float*)alloc((size_t)N * HH * 4);
    float* y      = (float*)alloc((size_t)N * DD * 4);
    float* xbuf   = (float*)alloc((size_t)N * DD * 4);
    float* pbuf   = (float*)alloc((size_t)NB_STATS * 192 * 4);
    float* scsh   = (float*)alloc(2 * DD * 4);
    float* wa     = (float*)alloc(2 * DD * 8 * 4);
    int*   deg    = (int*)alloc((size_t)N * 4);
    int*   locpre = (int*)alloc((size_t)N * 4);
    int*   bsum   = (int*)alloc(64 * 4);
    int*   rowptr = (int*)alloc((size_t)(N + 1) * 4);
    int*   cursor = (int*)alloc((size_t)N * 4);
    int*   colidx = (int*)alloc((size_t)Etot * 4);

    // ---- CSR by destination + WA precompute (layer-invariant structure) ----
    hipMemsetAsync(deg, 0, (size_t)N * 4, stream);
    count_kernel<<<1024, 256, 0, stream>>>(ei, deg, E);
    scan1_kernel<<<NBLK, 256, 0, stream>>>(deg, locpre, bsum, N);
    scan2_kernel<<<1, 64, 0, stream>>>(bsum, rowptr, NBLK, N);
    scan3_kernel<<<NBLK, 256, 0, stream>>>(locpre, bsum, rowptr, cursor, N);
    scatter_kernel<<<1024, 256, 0, stream>>>(ei, cursor, rowptr, colidx, E, Etot);
    wa_kernel<<<2 * DD, 64, 0, stream>>>(W, att_src, att_dst, wa);

    for (int l = 0; l < 2; l++) {
        const float* xin = (l == 0) ? x : xbuf;
        float* xout = (l == 1) ? out_final : xbuf;

        gemm_kernel<<<(N + GN - 1) / GN, 256, 0, stream>>>(
            xin, W + (size_t)l * DD * HD, wa + (size_t)l * DD * 8, hp, asrc, adst, N);
        agg_csr_kernel<<<(N * 64 + 255) / 256, 256, 0, stream>>>(
            rowptr, colidx, hp, asrc, adst, bias + (size_t)l * DD, y, N);
        bnstats_kernel<<<NB_STATS, 384, 0, stream>>>(y, pbuf, N * DD / 4);
        bnfin_kernel<<<1, DD, 0, stream>>>(pbuf, gamma + (size_t)l * DD,
                                           beta + (size_t)l * DD, scsh, N);
        bn_apply_kernel<<<2048, 256, 0, stream>>>(y, scsh, xin, xout, N * DD / 4);
    }
}